// Round 1
// baseline (72.304 us; speedup 1.0000x reference)
//
#include <hip/hip_runtime.h>

// SimilarityBasedFilter: bilateral depth filter, 5x5 window, zero padding.
// out = sum(v*w)/ (sum(w)+1e-6), w = exp(-(v-center)^2 / (2*0.1^2))
// Zero-padded OOB entries contribute v=0, w=exp(-center^2/0.02).

#define KW 5
#define PADR 2
#define TW 64
#define TH 8
#define LW (TW + 2 * PADR)   // 68
#define LH (TH + 2 * PADR)   // 12

__global__ __launch_bounds__(TW * TH) void sim_filter_kernel(
    const float* __restrict__ depth, float* __restrict__ out,
    int Bn, int H, int W) {
    __shared__ float tile[LH * LW];

    const int tx = threadIdx.x;           // 0..63
    const int ty = threadIdx.y;           // 0..7
    const int tid = ty * TW + tx;         // 0..511
    const int bx0 = blockIdx.x * TW;      // tile origin x
    const int by0 = blockIdx.y * TH;      // tile origin y
    const int b = blockIdx.z;

    const float* src = depth + (size_t)b * H * W;

    // cooperative halo load (zero padding)
    for (int i = tid; i < LH * LW; i += TW * TH) {
        int ly = i / LW;
        int lx = i - ly * LW;
        int gy = by0 + ly - PADR;
        int gx = bx0 + lx - PADR;
        float v = 0.0f;
        if (gy >= 0 && gy < H && gx >= 0 && gx < W)
            v = src[gy * W + gx];
        tile[i] = v;
    }
    __syncthreads();

    const float center = tile[(ty + PADR) * LW + (tx + PADR)];
    const float nscale = -50.0f;  // -1/(2*0.1^2)

    float wsum = 0.0f;
    float wtot = 0.0f;
#pragma unroll
    for (int dy = 0; dy < KW; ++dy) {
#pragma unroll
        for (int dx = 0; dx < KW; ++dx) {
            float v = tile[(ty + dy) * LW + (tx + dx)];
            float d = v - center;
            float w = __expf(d * d * nscale);
            wsum += v * w;
            wtot += w;
        }
    }

    const int gy = by0 + ty;
    const int gx = bx0 + tx;
    out[((size_t)b * H + gy) * W + gx] = wsum / (wtot + 1e-6f);
}

extern "C" void kernel_launch(void* const* d_in, const int* in_sizes, int n_in,
                              void* d_out, int out_size, void* d_ws, size_t ws_size,
                              hipStream_t stream) {
    const float* depth = (const float*)d_in[0];
    float* out = (float*)d_out;

    const int Bn = 8, H = 512, W = 512;
    dim3 block(TW, TH);
    dim3 grid(W / TW, H / TH, Bn);
    sim_filter_kernel<<<grid, block, 0, stream>>>(depth, out, Bn, H, W);
}